// Round 1
// baseline (582.173 us; speedup 1.0000x reference)
//
#include <hip/hip_runtime.h>
#include <stdint.h>

#define DEV __device__ __forceinline__
typedef unsigned short u16; typedef unsigned int u32; typedef unsigned long long u64;
typedef __attribute__((ext_vector_type(8))) short s8v;   // 8 x bf16 (4 VGPR)
typedef __attribute__((ext_vector_type(4))) float f4v;   // MFMA acc

#define Bb 512
#define Tt 256
#define Ff 64
#define Hh 128
#define Dd 192

DEV u16 f2bf(float f){ u32 u = __builtin_bit_cast(u32, f); u32 r = (u + 0x7fffu + ((u>>16)&1u)) >> 16; return (u16)r; }
DEV float bf2f(u16 h){ u32 u = ((u32)h)<<16; return __builtin_bit_cast(float, u); }
DEV float sigm(float x){ return __builtin_amdgcn_rcpf(1.0f + __expf(-x)); }
DEV float tanhfast(float x){ return 1.0f - 2.0f*__builtin_amdgcn_rcpf(1.0f + __expf(2.0f*x)); }

DEV f4v mfma16(s8v a, s8v b, f4v c){ return __builtin_amdgcn_mfma_f32_16x16x32_bf16(a, b, c, 0, 0, 0); }

// hx LDS element index for (k, col). Layout: [k/8 block][16 cols (xor-swizzled)][8 k]
// swizzle spreads the 4 k-subblocks of each 32-k tile across bank groups (2-way max = free).
DEV int hxe(int k, int c){ int blk = k>>3; return (blk*16 + (c ^ ((blk&3)<<1)))*8 + (k&7); }

DEV s8v pack8(const float* p){
  const float4 a = *(const float4*)p; const float4 b = *(const float4*)(p+4);
  s8v r; r[0]=(short)f2bf(a.x); r[1]=(short)f2bf(a.y); r[2]=(short)f2bf(a.z); r[3]=(short)f2bf(a.w);
  r[4]=(short)f2bf(b.x); r[5]=(short)f2bf(b.y); r[6]=(short)f2bf(b.z); r[7]=(short)f2bf(b.w); return r;
}

// ---------------- prelim: last_obs, x_last, score const term ----------------
__global__ __launch_bounds__(64) void prelim_k(const float* __restrict__ x,
    const float* __restrict__ Watt, const float* __restrict__ batt,
    float* __restrict__ xlast, float* __restrict__ c0, int* __restrict__ lastobs)
{
  int b = blockIdx.x, tid = threadIdx.x;
  int cnt = 0;
  for (int it = 0; it < 4; ++it){
    int t = it*64 + tid;
    const float4* p = (const float4*)(x + ((size_t)b*Tt + t)*Ff);
    float s = 0.0f;
    #pragma unroll
    for (int q = 0; q < 16; ++q){ float4 v = p[q]; s += fabsf(v.x)+fabsf(v.y)+fabsf(v.z)+fabsf(v.w); }
    u64 m = __ballot(s != 0.0f);
    cnt += __popcll(m);
  }
  int last = cnt - 1;
  int li = (last < 0) ? (Tt-1) : last;     // jnp negative index wraps
  float xl = x[((size_t)b*Tt + li)*Ff + tid];
  xlast[b*Ff + tid] = xl;
  float p = xl * Watt[Hh + tid];
  for (int off = 32; off; off >>= 1) p += __shfl_down(p, off);
  if (tid == 0){ c0[b] = p + batt[0]; lastobs[b] = last; }
}

// ---------------- decoder weight prep: frag-major bf16 ----------------
__global__ __launch_bounds__(256) void prep_wd_k(const float* __restrict__ Whhcs, u16* __restrict__ Wd)
{
  int idx = blockIdx.x*256 + threadIdx.x;          // < 2*768*192 = 294912
  int j = idx & 7, l = (idx>>3)&63;
  int fidx = idx>>9;
  int kt = fidx % 6; int rem = fidx/6; int mt = rem & 3; rem >>= 2; int w = rem % 12; int r = rem/12;
  int gate = mt*Dd + w*16 + (l&15);
  int k = kt*32 + (l>>4)*8 + j;
  Wd[idx] = f2bf(Whhcs[((size_t)r*768 + gate)*Dd + k]);
}

// ---------------- encoder: LSTM + fused long_pred + fused online attention ----------------
__global__ __launch_bounds__(512) void enc_k(
    const float* __restrict__ x, const float* __restrict__ Whh, const float* __restrict__ Wih,
    const float* __restrict__ Wlong, const float* __restrict__ blong, const float* __restrict__ Watt,
    const float* __restrict__ xlast, const float* __restrict__ c0v, const int* __restrict__ lastobs,
    float* __restrict__ lp_out, float* __restrict__ ha)
{
  __shared__ __align__(16) u16 hx[3072];     // [K=192][16 rows] bf16, swizzled
  __shared__ float lp_lds[16*68];
  __shared__ float sarr[16];
  const int tid = threadIdx.x, wid = tid>>6, lane = tid&63, l15 = lane&15, l4 = lane>>4;
  const int b0 = blockIdx.x*16;
  const int xrow = tid>>5, xc2 = (tid&31)*2;

  // A-fragments: gates (all 8 waves own 16 cell units each), M = gate rows
  s8v wf[4][6];
  #pragma unroll
  for (int mt = 0; mt < 4; ++mt){
    int gate = mt*Hh + wid*16 + l15;
    #pragma unroll
    for (int kt = 0; kt < 6; ++kt){
      int k0 = kt*32 + l4*8;
      if (kt < 4) wf[mt][kt] = pack8(Whh + (size_t)gate*Hh + k0);
      else        wf[mt][kt] = pack8(Wih + (size_t)gate*Ff + (k0 - Hh));
    }
  }
  // extra tile: waves 0-3 -> long_pred features, wave 4 -> attention score row
  s8v wfx[6];
  {
    s8v z = {0,0,0,0,0,0,0,0};
    #pragma unroll
    for (int kt = 0; kt < 6; ++kt) wfx[kt] = z;
    if (wid < 4){
      int f = wid*16 + l15;
      #pragma unroll
      for (int kt = 0; kt < 4; ++kt) wfx[kt] = pack8(Wlong + (size_t)f*Hh + kt*32 + l4*8);
    } else if (wid == 4 && l15 == 0){
      #pragma unroll
      for (int kt = 0; kt < 4; ++kt) wfx[kt] = pack8(Watt + kt*32 + l4*8);
    }
  }
  float bl[4] = {0,0,0,0};
  if (wid < 4){
    #pragma unroll
    for (int j = 0; j < 4; ++j) bl[j] = blong[wid*16 + l4*4 + j];
  }
  const int   lastb = lastobs[b0 + l15];
  const float c0b   = c0v[b0 + l15];

  // init LDS: h = 0 (elements 0..2047), x_0 into k=128..191
  ((u64*)hx)[tid] = 0ull;
  {
    float2 xv = *(const float2*)(x + ((size_t)(b0+xrow)*Tt + 0)*Ff + xc2);
    u32 pk = (u32)f2bf(xv.x) | ((u32)f2bf(xv.y)<<16);
    *(u32*)&hx[hxe(Hh + xc2, xrow)] = pk;
  }
  __syncthreads();

  float cst[4] = {0,0,0,0}, hval[4] = {0,0,0,0};
  float accA[4] = {0,0,0,0}, mrun = -3.0e38f, zrun = 0.0f;

  for (int t = 0; t < Tt; ++t){
    s8v bf[6];
    #pragma unroll
    for (int kt = 0; kt < 6; ++kt)
      bf[kt] = *(const s8v*)&hx[((kt*4 + l4)*16 + (l15 ^ (l4<<1)))*8];
    float2 xnext;
    if (t+1 < Tt) xnext = *(const float2*)(x + ((size_t)(b0+xrow)*Tt + (t+1))*Ff + xc2);

    f4v acc0 = {0,0,0,0}, acc1 = {0,0,0,0}, acc2 = {0,0,0,0}, acc3 = {0,0,0,0}, accx = {0,0,0,0};
    #pragma unroll
    for (int kt = 0; kt < 6; ++kt){
      acc0 = mfma16(wf[0][kt], bf[kt], acc0);
      acc1 = mfma16(wf[1][kt], bf[kt], acc1);
      acc2 = mfma16(wf[2][kt], bf[kt], acc2);
      acc3 = mfma16(wf[3][kt], bf[kt], acc3);
    }
    if (wid < 5){
      #pragma unroll
      for (int kt = 0; kt < 6; ++kt) accx = mfma16(wfx[kt], bf[kt], accx);
    }
    if (wid == 4 && l4 == 0) sarr[l15] = accx[0] + c0b;   // s_{t-1}

    float hnew[4];
    #pragma unroll
    for (int j = 0; j < 4; ++j){
      float cn = sigm(acc1[j])*cst[j] + sigm(acc0[j])*tanhfast(acc2[j]);
      cst[j] = cn;
      hnew[j] = sigm(acc3[j])*tanhfast(cn);
    }
    __syncthreads();                                       // barrier 1
    if (t >= 1){
      float s = sarr[l15];
      if (t-1 < lastb){                                    // online softmax-weighted sum of h_{t-1}
        float mn = fmaxf(mrun, s);
        float sc = __expf(mrun - mn);
        float e  = __expf(s - mn);
        zrun = zrun*sc + e;
        #pragma unroll
        for (int j = 0; j < 4; ++j) accA[j] = accA[j]*sc + e*hval[j];
        mrun = mn;
      }
    }
    #pragma unroll
    for (int j = 0; j < 4; ++j) hval[j] = hnew[j];
    #pragma unroll
    for (int j = 0; j < 4; ++j) hx[hxe(wid*16 + l4*4 + j, l15)] = (u16)f2bf(hnew[j]);
    if (t+1 < Tt){
      u32 pk = (u32)f2bf(xnext.x) | ((u32)f2bf(xnext.y)<<16);
      *(u32*)&hx[hxe(Hh + xc2, xrow)] = pk;
    }
    if (wid < 4){
      #pragma unroll
      for (int j = 0; j < 4; ++j)
        lp_lds[l15*68 + wid*16 + l4*4 + j] = accx[j] + bl[j];  // long_pred[t-1]
    }
    __syncthreads();                                       // barrier 2
    if (t >= 1){
      float2 v; v.x = lp_lds[xrow*68 + xc2]; v.y = lp_lds[xrow*68 + xc2 + 1];
      *(float2*)(lp_out + ((size_t)(b0+xrow)*Tt + (t-1))*Ff + xc2) = v;
    }
  }
  // epilogue: long_pred[255] from h_255, write ha
  {
    s8v bf[4];
    #pragma unroll
    for (int kt = 0; kt < 4; ++kt)
      bf[kt] = *(const s8v*)&hx[((kt*4 + l4)*16 + (l15 ^ (l4<<1)))*8];
    if (wid < 4){
      f4v accx = {0,0,0,0};
      #pragma unroll
      for (int kt = 0; kt < 4; ++kt) accx = mfma16(wfx[kt], bf[kt], accx);
      #pragma unroll
      for (int j = 0; j < 4; ++j) lp_lds[l15*68 + wid*16 + l4*4 + j] = accx[j] + bl[j];
    }
    float inv = (zrun > 0.0f) ? __builtin_amdgcn_rcpf(zrun) : 0.0f;
    #pragma unroll
    for (int j = 0; j < 4; ++j)
      ha[(size_t)(b0 + l15)*Dd + wid*16 + l4*4 + j] = accA[j]*inv;
    __syncthreads();
    { float2 v; v.x = lp_lds[xrow*68 + xc2]; v.y = lp_lds[xrow*68 + xc2 + 1];
      *(float2*)(lp_out + ((size_t)(b0+xrow)*Tt + (Tt-1))*Ff + xc2) = v; }
    for (int q = tid; q < 16*Ff; q += 512){
      int r2 = q >> 6, f = q & 63;
      ha[(size_t)(b0 + r2)*Dd + Hh + f] = xlast[(b0 + r2)*Ff + f];
    }
  }
}

// ---------------- decoder: 64-step alternating-risk LSTM chain ----------------
__global__ __launch_bounds__(768) void dec_k(const float* __restrict__ ha, const u16* __restrict__ Wd,
    const float* __restrict__ Wihcs, const float* __restrict__ Wcs, const float* __restrict__ bcs,
    float* __restrict__ outs)
{
  __shared__ __align__(16) u16 hx[3072];
  __shared__ float red[16*52];
  const int tid = threadIdx.x, wid = tid>>6, lane = tid&63, l15 = lane&15, l4 = lane>>4;
  const int b0 = blockIdx.x*16;
  {
    int k4 = tid>>4, c = tid&15, k = k4*4;
    float4 v = *(const float4*)(ha + (size_t)(b0+c)*Dd + k);
    int e = hxe(k, c);
    *(u32*)&hx[e]   = (u32)f2bf(v.x) | ((u32)f2bf(v.y)<<16);
    *(u32*)&hx[e+2] = (u32)f2bf(v.z) | ((u32)f2bf(v.w)<<16);
  }
  const int u0 = wid*16 + l4*4;
  float cst[4], wcs0[4], wcs1[4];
  #pragma unroll
  for (int j = 0; j < 4; ++j){
    cst[j]  = ha[(size_t)(b0+l15)*Dd + u0 + j];
    wcs0[j] = Wcs[u0 + j];
    wcs1[j] = Wcs[Dd + u0 + j];
  }
  const float bc0 = bcs[0], bc1 = bcs[1];
  __syncthreads();
  // xw[r][mt] = ha @ W_ih_cs[r]^T fragments (constant across steps)
  f4v xw0[4], xw1[4];
  {
    s8v haf[6];
    #pragma unroll
    for (int kt = 0; kt < 6; ++kt)
      haf[kt] = *(const s8v*)&hx[((kt*4 + l4)*16 + (l15 ^ (l4<<1)))*8];
    #pragma unroll
    for (int r = 0; r < 2; ++r)
      #pragma unroll
      for (int mt = 0; mt < 4; ++mt){
        f4v a = {0,0,0,0};
        #pragma unroll
        for (int kt = 0; kt < 6; ++kt){
          int gate = mt*Dd + wid*16 + l15;
          s8v w = pack8(Wihcs + ((size_t)r*768 + gate)*Dd + kt*32 + l4*8);
          a = mfma16(w, haf[kt], a);
        }
        if (r == 0) xw0[mt] = a; else xw1[mt] = a;
      }
  }
  for (int s = 0; s < 64; ++s){
    const int r = s & 1;
    s8v bf[6];
    #pragma unroll
    for (int kt = 0; kt < 6; ++kt)
      bf[kt] = *(const s8v*)&hx[((kt*4 + l4)*16 + (l15 ^ (l4<<1)))*8];
    const u16* wb = Wd + ((size_t)(r*12 + wid)*24)*512 + lane*8;
    f4v acc[4];
    s8v w0[6], w1[6];
    #pragma unroll
    for (int kt = 0; kt < 6; ++kt) w0[kt] = *(const s8v*)(wb + kt*512);
    { // mt = 0 (prefetch mt=1 into w1)
      #pragma unroll
      for (int kt = 0; kt < 6; ++kt) w1[kt] = *(const s8v*)(wb + (6 + kt)*512);
      f4v a = r ? xw1[0] : xw0[0];
      #pragma unroll
      for (int kt = 0; kt < 6; ++kt) a = mfma16(w0[kt], bf[kt], a);
      acc[0] = a;
    }
    { // mt = 1
      #pragma unroll
      for (int kt = 0; kt < 6; ++kt) w0[kt] = *(const s8v*)(wb + (12 + kt)*512);
      f4v a = r ? xw1[1] : xw0[1];
      #pragma unroll
      for (int kt = 0; kt < 6; ++kt) a = mfma16(w1[kt], bf[kt], a);
      acc[1] = a;
    }
    { // mt = 2
      #pragma unroll
      for (int kt = 0; kt < 6; ++kt) w1[kt] = *(const s8v*)(wb + (18 + kt)*512);
      f4v a = r ? xw1[2] : xw0[2];
      #pragma unroll
      for (int kt = 0; kt < 6; ++kt) a = mfma16(w0[kt], bf[kt], a);
      acc[2] = a;
    }
    { // mt = 3
      f4v a = r ? xw1[3] : xw0[3];
      #pragma unroll
      for (int kt = 0; kt < 6; ++kt) a = mfma16(w1[kt], bf[kt], a);
      acc[3] = a;
    }
    float hnew[4], part = 0.0f;
    #pragma unroll
    for (int j = 0; j < 4; ++j){
      float cn = sigm(acc[1][j])*cst[j] + sigm(acc[0][j])*tanhfast(acc[2][j]);
      cst[j] = cn;
      hnew[j] = sigm(acc[3][j])*tanhfast(cn);
      part += hnew[j] * (r ? wcs1[j] : wcs0[j]);
    }
    __syncthreads();
    #pragma unroll
    for (int j = 0; j < 4; ++j) hx[hxe(u0 + j, l15)] = (u16)f2bf(hnew[j]);
    red[l15*52 + wid*4 + l4] = part;
    __syncthreads();
    if (tid < 16){
      float ssum = 0.0f;
      #pragma unroll
      for (int q = 0; q < 48; ++q) ssum += red[tid*52 + q];
      outs[s*Bb + b0 + tid] = sigm(ssum + (r ? bc1 : bc0));
    }
  }
}

// ---------------- final softmax over 64 steps ----------------
__global__ __launch_bounds__(256) void fin_k(const float* __restrict__ outs, float* __restrict__ dout)
{
  int row = blockIdx.x*256 + threadIdx.x;
  float v[64]; float mx = -3.0e38f;
  #pragma unroll
  for (int s = 0; s < 64; ++s){ v[s] = outs[s*Bb + row]; mx = fmaxf(mx, v[s]); }
  float sum = 0.0f;
  #pragma unroll
  for (int s = 0; s < 64; ++s){ v[s] = __expf(v[s] - mx); sum += v[s]; }
  float inv = __builtin_amdgcn_rcpf(sum);
  float* p0 = dout + (size_t)Bb*Tt*Ff;
  float* p1 = p0 + Bb*32;
  #pragma unroll
  for (int j = 0; j < 32; ++j) p0[row*32 + j] = v[j]*inv;
  #pragma unroll
  for (int j = 0; j < 32; ++j) p1[row*32 + j] = v[32 + j]*inv;
}

extern "C" void kernel_launch(void* const* d_in, const int* in_sizes, int n_in,
                              void* d_out, int out_size, void* d_ws, size_t ws_size,
                              hipStream_t stream)
{
  const float* x      = (const float*)d_in[0];
  const float* Wih    = (const float*)d_in[1];
  const float* Whh    = (const float*)d_in[2];
  const float* Wlong  = (const float*)d_in[3];
  const float* blong  = (const float*)d_in[4];
  const float* Watt   = (const float*)d_in[5];
  const float* batt   = (const float*)d_in[6];
  const float* Wihcs  = (const float*)d_in[7];
  const float* Whhcs  = (const float*)d_in[8];
  const float* Wcs    = (const float*)d_in[9];
  const float* bcs    = (const float*)d_in[10];
  float* out = (float*)d_out;
  char* ws = (char*)d_ws;

  float* xlast   = (float*)ws;                 // 512*64*4      = 131072
  float* c0      = (float*)(ws + 131072);      // 512*4         = 2048
  int*   lastobs = (int*)  (ws + 133120);      // 512*4         = 2048
  float* ha      = (float*)(ws + 135168);      // 512*192*4     = 393216
  u16*   Wd      = (u16*)  (ws + 528384);      // 2*768*192*2   = 589824
  float* outs    = (float*)(ws + 1118208);     // 64*512*4      = 131072

  prep_wd_k<<<1152, 256, 0, stream>>>(Whhcs, Wd);
  prelim_k<<<Bb, 64, 0, stream>>>(x, Watt, batt, xlast, c0, lastobs);
  enc_k<<<32, 512, 0, stream>>>(x, Whh, Wih, Wlong, blong, Watt, xlast, c0, lastobs, out, ha);
  dec_k<<<32, 768, 0, stream>>>(ha, Wd, Wihcs, Wcs, bcs, outs);
  fin_k<<<2, 256, 0, stream>>>(outs, out);
}